// Round 1
// baseline (784.266 us; speedup 1.0000x reference)
//
#include <hip/hip_runtime.h>

// mu_out = relu(mu_in), tiny (131072 elems)
__global__ void relu_mu_kernel(const float* __restrict__ mu,
                               float* __restrict__ out, int n) {
    int idx = blockIdx.x * blockDim.x + threadIdx.x;
    if (idx < n) {
        float v = mu[idx];
        out[idx] = v > 0.f ? v : 0.f;
    }
}

// One block per output row (b, i). 256 threads, float4 per thread iteration.
// If gradi[b,i] == 0 the whole row is zero: skip the Sigma read entirely
// (saves ~50% of HBM fetch traffic; branch is block-uniform, no divergence).
__global__ void __launch_bounds__(256)
sigma_kernel(const float* __restrict__ mu,
             const float* __restrict__ Sigma,
             float* __restrict__ out, int D) {
    const int row = blockIdx.x;     // row = b*D + i
    const int b   = row / D;        // scalar div once per block, cheap
    const float gi = mu[row];       // mu is row-major (B,D): mu[b*D+i] == mu[row]

    const size_t row_off = (size_t)row * (size_t)D;
    const float4* __restrict__ S4  = (const float4*)(Sigma + row_off);
    float4* __restrict__       O4  = (float4*)(out + row_off);
    const float4* __restrict__ mu4 = (const float4*)(mu + (size_t)b * (size_t)D);
    const int n4 = D >> 2;

    if (gi <= 0.f) {
        const float4 z = make_float4(0.f, 0.f, 0.f, 0.f);
        for (int t = threadIdx.x; t < n4; t += blockDim.x) O4[t] = z;
    } else {
        for (int t = threadIdx.x; t < n4; t += blockDim.x) {
            float4 m = mu4[t];   // gradi[b, 4t..4t+3] source; L2-resident
            float4 s = S4[t];
            float4 r;
            r.x = m.x > 0.f ? s.x : 0.f;
            r.y = m.y > 0.f ? s.y : 0.f;
            r.z = m.z > 0.f ? s.z : 0.f;
            r.w = m.w > 0.f ? s.w : 0.f;
            O4[t] = r;
        }
    }
}

extern "C" void kernel_launch(void* const* d_in, const int* in_sizes, int n_in,
                              void* d_out, int out_size, void* d_ws, size_t ws_size,
                              hipStream_t stream) {
    const float* mu    = (const float*)d_in[0];
    const float* Sigma = (const float*)d_in[1];
    float* out = (float*)d_out;

    const int n_mu = in_sizes[0];              // B*D = 131072
    const int D    = in_sizes[1] / in_sizes[0];// 1024
    const int rows = n_mu;                     // B*D rows of Sigma

    relu_mu_kernel<<<(n_mu + 255) / 256, 256, 0, stream>>>(mu, out, n_mu);
    sigma_kernel<<<rows, 256, 0, stream>>>(mu, Sigma, out + n_mu, D);
}

// Round 2
// 781.402 us; speedup vs baseline: 1.0037x; 1.0037x over previous
//
#include <hip/hip_runtime.h>

typedef float f4 __attribute__((ext_vector_type(4)));

// mu_out = relu(mu_in), tiny (131072 elems)
__global__ void relu_mu_kernel(const float* __restrict__ mu,
                               float* __restrict__ out, int n) {
    int idx = blockIdx.x * blockDim.x + threadIdx.x;
    if (idx < n) {
        float v = mu[idx];
        out[idx] = v > 0.f ? v : 0.f;
    }
}

// 256 threads = 4 waves per block; wave w handles row 4*blockIdx + w.
// Each wave covers D=1024 floats in 4 float4 iterations -> 4 independent
// loads in flight per thread (MLP=4). Sigma/out are streamed with
// nontemporal load/store (no reuse, keep L2 for mu); mu loads stay cached.
// gi <= 0 rows skip the Sigma read entirely (wave-uniform branch).
__global__ void __launch_bounds__(256)
sigma_kernel(const float* __restrict__ mu,
             const float* __restrict__ Sigma,
             float* __restrict__ out, int D, int rows_total) {
    const int wave = threadIdx.x >> 6;
    const int lane = threadIdx.x & 63;
    const int row  = (blockIdx.x << 2) + wave;
    if (row >= rows_total) return;

    const int b = row / D;          // once per wave, scalar
    const float gi = mu[row];       // cached; same addr across wave -> broadcast

    const size_t row_off = (size_t)row * (size_t)D;
    const f4* __restrict__ S4  = (const f4*)(Sigma + row_off);
    f4* __restrict__       O4  = (f4*)(out + row_off);
    const f4* __restrict__ mu4 = (const f4*)(mu + (size_t)b * (size_t)D);
    const int n4 = D >> 2;          // 256 for D=1024; 4 iters per wave

    if (gi <= 0.f) {
        f4 z = (f4)0.f;
        #pragma unroll 4
        for (int t = lane; t < n4; t += 64)
            __builtin_nontemporal_store(z, O4 + t);
    } else {
        #pragma unroll 4
        for (int t = lane; t < n4; t += 64) {
            f4 m = mu4[t];                              // L1/L2 hit
            f4 s = __builtin_nontemporal_load(S4 + t);  // stream from HBM
            f4 r;
            r[0] = m[0] > 0.f ? s[0] : 0.f;
            r[1] = m[1] > 0.f ? s[1] : 0.f;
            r[2] = m[2] > 0.f ? s[2] : 0.f;
            r[3] = m[3] > 0.f ? s[3] : 0.f;
            __builtin_nontemporal_store(r, O4 + t);     // stream to HBM
        }
    }
}

extern "C" void kernel_launch(void* const* d_in, const int* in_sizes, int n_in,
                              void* d_out, int out_size, void* d_ws, size_t ws_size,
                              hipStream_t stream) {
    const float* mu    = (const float*)d_in[0];
    const float* Sigma = (const float*)d_in[1];
    float* out = (float*)d_out;

    const int n_mu = in_sizes[0];               // B*D = 131072
    const int D    = in_sizes[1] / in_sizes[0]; // 1024
    const int rows = n_mu;                      // B*D rows of Sigma

    relu_mu_kernel<<<(n_mu + 255) / 256, 256, 0, stream>>>(mu, out, n_mu);
    sigma_kernel<<<(rows + 3) / 4, 256, 0, stream>>>(mu, Sigma, out + n_mu, D, rows);
}